// Round 1
// baseline (549.820 us; speedup 1.0000x reference)
//
#include <hip/hip_runtime.h>
#include <stdint.h>

#define TREES 8192
#define HID   256
#define CH    16
#define KL    4
#define GB    16           // trees per block
#define CKT   4            // trees per chunk
#define NC    (GB / CKT)   // 4 chunks per block
#define LDSS  264          // LDS row stride in bf16 elems (256 + 8 pad)

typedef short bf16x8 __attribute__((ext_vector_type(8)));
typedef float f32x4  __attribute__((ext_vector_type(4)));

__device__ __forceinline__ unsigned short f2bf(float f) {
    unsigned u = __builtin_bit_cast(unsigned, f);
    u += 0x7FFFu + ((u >> 16) & 1u);
    return (unsigned short)(u >> 16);
}
__device__ __forceinline__ float elu1(float x) {
    return x > 0.f ? x : (__expf(x) - 1.f);
}
__device__ __forceinline__ uint4 pack8(float4 a, float4 b) {
    union { uint4 u4; unsigned short s[8]; } U;
    U.s[0] = f2bf(a.x); U.s[1] = f2bf(a.y); U.s[2] = f2bf(a.z); U.s[3] = f2bf(a.w);
    U.s[4] = f2bf(b.x); U.s[5] = f2bf(b.y); U.s[6] = f2bf(b.z); U.s[7] = f2bf(b.w);
    return U.u4;
}

// ---- Prep: tiled transpose fp32 [h][d] -> bf16 [d][h], coalesced both sides.
// grid (4,4,5): z = 0..3 -> Wz layer k, z = 4 -> Wzf. Block (0,0,4) also does bzsum.
__global__ void prep_transpose(const float* __restrict__ Wz,
                               const float* __restrict__ Wzf,
                               const float* __restrict__ bz,
                               unsigned short* __restrict__ WzT,
                               unsigned short* __restrict__ WzfT,
                               float* __restrict__ bzsum) {
    __shared__ unsigned short ts[64][65];
    const int k  = blockIdx.z;
    const int h0 = blockIdx.x * 64;
    const int d0 = blockIdx.y * 64;
    const float* src = (k < KL) ? (Wz + (k << 16)) : Wzf;
    unsigned short* dst = (k < KL) ? (WzT + (k << 16)) : WzfT;
    const int tid = threadIdx.x;
    const int jc  = tid & 63;
    #pragma unroll
    for (int r = 0; r < 16; ++r) {
        int i = r * 4 + (tid >> 6);
        ts[jc][i] = f2bf(src[(h0 + i) * HID + d0 + jc]);   // coalesced read
    }
    __syncthreads();
    #pragma unroll
    for (int r = 0; r < 16; ++r) {
        int jl = r * 4 + (tid >> 6);
        dst[(d0 + jl) * HID + h0 + jc] = ts[jl][jc];       // coalesced write
    }
    // merged bz_sum (one block only) — saves a kernel launch
    if (k == KL && blockIdx.x == 0 && blockIdx.y == 0) {
        float s = 0.f;
        #pragma unroll
        for (int kk = 0; kk < KL; ++kk) s += bz[kk * HID + tid];
        bzsum[tid] = s;
    }
}

// ---- Main: 16 trees/block in 4 chunks of 4 trees, double-buffered LDS.
// While chunk c runs GEMM1 (32 MFMA steps), chunk c+1's x rows are loaded
// (issue-early) and ds-written into the other buffer (write-late). Leaf
// indices are prefetched one chunk further ahead. Weights use a depth-2
// rotating prefetch (period 32 -> slot phase survives chunk boundaries).
__global__ __launch_bounds__(256, 2) void ptree_kernel(
    const float* __restrict__ x,               // [N,256] fp32
    const int* __restrict__ leaf,              // [T,16]
    const float* __restrict__ bzf,             // [256] fp32
    const unsigned short* __restrict__ WzT,    // [K][d][h] bf16 (ws)
    const unsigned short* __restrict__ WzfT,   // [d][h] bf16 (ws)
    const float* __restrict__ bzsum,           // [256] f32 (ws)
    float* __restrict__ out,                   // [T,256] fp32
    int nrows)
{
    __shared__ __align__(16) unsigned short sh[2][CKT][CH][LDSS]; // 2 x 33 KB
    __shared__ __align__(16) unsigned short hs[GB][LDSS];         // 16 tree rows
    const int tid  = threadIdx.x;
    const int lane = tid & 63;
    const int wave = tid >> 6;
    const int t0   = blockIdx.x * GB;
    const int ncol = lane & 15;
    const int quad = lane >> 4;
    const int ch   = tid & 31;   // 8-float column chunk within a row
    const int q5   = tid >> 5;   // 0..7
    // per-thread cell i (0..7): tree g = i>>1, child row = ((i&1)<<3)+q5

    // ---- prologue: gather chunk 0 straight into sh[0]
    #pragma unroll
    for (int i = 0; i < 8; ++i) {
        const int g = i >> 1, row = ((i & 1) << 3) + q5;
        int idx = leaf[(t0 + g) * CH + row];
        idx = ((unsigned)idx < (unsigned)nrows) ? idx : 0;
        const float* src = x + (size_t)idx * HID + ch * 8;
        float4 v0 = *(const float4*)src;
        float4 v1 = *(const float4*)(src + 4);
        *(uint4*)&sh[0][g][row][ch * 8] = pack8(v0, v1);
    }
    // leaf-index prefetch for chunk 1
    int idxp[8];
    #pragma unroll
    for (int i = 0; i < 8; ++i) {
        const int g = i >> 1, row = ((i & 1) << 3) + q5;
        int idx = leaf[(t0 + CKT + g) * CH + row];
        idxp[i] = ((unsigned)idx < (unsigned)nrows) ? idx : 0;
    }

    float bzs[4], bzfv[4];
    #pragma unroll
    for (int nt = 0; nt < 4; ++nt) {
        bzs[nt]  = bzsum[wave * 64 + nt * 16 + ncol];
        bzfv[nt] = bzf[wave * 64 + nt * 16 + ncol];
    }

    // weight fragment pipeline, depth 2 (slot = s&1; 32%2==0 -> chunk-periodic)
    const unsigned short* wz_base = WzT + (wave * 64 + ncol) * HID + quad * 8;
    bf16x8 bp[2][4];
    #pragma unroll
    for (int s = 0; s < 2; ++s) {
        const unsigned short* p = wz_base + (s >> 3) * 65536 + (s & 7) * 32;
        #pragma unroll
        for (int nt = 0; nt < 4; ++nt) bp[s][nt] = *(const bf16x8*)(p + nt * 16 * HID);
    }

    __syncthreads();

    for (int c = 0; c < NC; ++c) {
        const int pb   = c & 1;
        const int more = (c < NC - 1);

        float4 xa[8], xb[8];
        // issue batch0 (cells 0..3 of chunk c+1) before any MFMA
        if (more) {
            #pragma unroll
            for (int i = 0; i < 4; ++i) {
                const float* src = x + (size_t)idxp[i] * HID + ch * 8;
                xa[2 * i]     = *(const float4*)src;
                xa[2 * i + 1] = *(const float4*)(src + 4);
            }
        }

        f32x4 acc1[CKT][4];
        #pragma unroll
        for (int g = 0; g < CKT; ++g)
            #pragma unroll
            for (int nt = 0; nt < 4; ++nt) acc1[g][nt] = f32x4{0.f, 0.f, 0.f, 0.f};

        #pragma unroll
        for (int k = 0; k < KL; ++k) {
            if (k == 1 && more) {        // issue batch1 (cells 4..7)
                #pragma unroll
                for (int i = 4; i < 8; ++i) {
                    const float* src = x + (size_t)idxp[i] * HID + ch * 8;
                    xb[2 * (i - 4)]     = *(const float4*)src;
                    xb[2 * (i - 4) + 1] = *(const float4*)(src + 4);
                }
            }
            if (k == 2 && more) {        // write-back batch0 into the free buffer
                #pragma unroll
                for (int i = 0; i < 4; ++i) {
                    const int g = i >> 1, row = ((i & 1) << 3) + q5;
                    *(uint4*)&sh[pb ^ 1][g][row][ch * 8] = pack8(xa[2 * i], xa[2 * i + 1]);
                }
                if (c + 2 < NC) {        // leaf indices for chunk c+2
                    #pragma unroll
                    for (int i = 0; i < 8; ++i) {
                        const int g = i >> 1, row = ((i & 1) << 3) + q5;
                        int idx = leaf[(t0 + (c + 2) * CKT + g) * CH + row];
                        idxp[i] = ((unsigned)idx < (unsigned)nrows) ? idx : 0;
                    }
                }
            }
            if (k == 3 && more) {        // write-back batch1
                #pragma unroll
                for (int i = 4; i < 8; ++i) {
                    const int g = i >> 1, row = ((i & 1) << 3) + q5;
                    *(uint4*)&sh[pb ^ 1][g][row][ch * 8] =
                        pack8(xb[2 * (i - 4)], xb[2 * (i - 4) + 1]);
                }
            }
            const int arow = (ncol - k) & 15;
            #pragma unroll
            for (int kt = 0; kt < 8; ++kt) {
                const int s = k * 8 + kt;
                #pragma unroll
                for (int g = 0; g < CKT; ++g) {
                    bf16x8 a = *(const bf16x8*)&sh[pb][g][arow][kt * 32 + quad * 8];
                    #pragma unroll
                    for (int nt = 0; nt < 4; ++nt)
                        acc1[g][nt] = __builtin_amdgcn_mfma_f32_16x16x32_bf16(
                            a, bp[s & 1][nt], acc1[g][nt], 0, 0, 0);
                }
                // prefetch weights for step s+2 into the slot just consumed
                const int sn = (s + 2) & 31;
                const unsigned short* pn = wz_base + (sn >> 3) * 65536 + (sn & 7) * 32;
                #pragma unroll
                for (int nt = 0; nt < 4; ++nt)
                    bp[s & 1][nt] = *(const bf16x8*)(pn + nt * 16 * HID);
            }
        }

        // hsum: +bz, ELU, sum over 16 children -> hs row (c*4+g)
        #pragma unroll
        for (int g = 0; g < CKT; ++g)
            #pragma unroll
            for (int nt = 0; nt < 4; ++nt) {
                float sv = 0.f;
                #pragma unroll
                for (int r = 0; r < 4; ++r) sv += elu1(acc1[g][nt][r] + bzs[nt]);
                sv += __shfl_xor(sv, 16);
                sv += __shfl_xor(sv, 32);
                if (quad == 0) hs[c * CKT + g][wave * 64 + nt * 16 + ncol] = f2bf(sv);
            }

        __syncthreads();   // next-buffer writes visible; current-buffer reads done
    }

    // ---- GEMM2: all 16 hs rows valid -> no masking, no wasted rows.
    f32x4 acc2[4];
    #pragma unroll
    for (int nt = 0; nt < 4; ++nt) acc2[nt] = f32x4{0.f, 0.f, 0.f, 0.f};

    const unsigned short* wzf_base = WzfT + (wave * 64 + ncol) * HID + quad * 8;
    #pragma unroll
    for (int kt = 0; kt < 8; ++kt) {
        bf16x8 a = *(const bf16x8*)&hs[ncol][kt * 32 + quad * 8];
        #pragma unroll
        for (int nt = 0; nt < 4; ++nt) {
            bf16x8 b = *(const bf16x8*)(wzf_base + nt * 16 * HID + kt * 32);
            acc2[nt] = __builtin_amdgcn_mfma_f32_16x16x32_bf16(a, b, acc2[nt], 0, 0, 0);
        }
    }

    #pragma unroll
    for (int nt = 0; nt < 4; ++nt)
        #pragma unroll
        for (int r = 0; r < 4; ++r) {
            const int tree = quad * 4 + r;   // 0..15, all valid
            float v = elu1(acc2[nt][r] + 16.f * bzfv[nt]);
            out[(size_t)(t0 + tree) * HID + wave * 64 + nt * 16 + ncol] = v;
        }
}

extern "C" void kernel_launch(void* const* d_in, const int* in_sizes, int n_in,
                              void* d_out, int out_size, void* d_ws, size_t ws_size,
                              hipStream_t stream) {
    (void)out_size; (void)ws_size;
    const void* p_x = nullptr; const void* p_Wz = nullptr; const void* p_bz = nullptr;
    const void* p_Wzf = nullptr; const void* p_bzf = nullptr; const void* p_leaf = nullptr;
    for (int i = 0; i < n_in; ++i) {
        switch (in_sizes[i]) {
            case 200000 * 256:   p_x    = d_in[i]; break;
            case KL * 256 * 256: p_Wz   = d_in[i]; break;
            case KL * 256:       p_bz   = d_in[i]; break;
            case 256 * 256:      p_Wzf  = d_in[i]; break;
            case 256:            p_bzf  = d_in[i]; break;
            case TREES * CH:     p_leaf = d_in[i]; break;
        }
    }
    const float* x    = (const float*)p_x;
    const float* Wz   = (const float*)p_Wz;
    const float* bz   = (const float*)p_bz;
    const float* Wzf  = (const float*)p_Wzf;
    const float* bzf  = (const float*)p_bzf;
    const int*   leaf = (const int*)p_leaf;

    unsigned short* WzT  = (unsigned short*)d_ws;        // 512 KB
    unsigned short* WzfT = WzT + KL * HID * HID;         // 128 KB
    float*          bzsum = (float*)(WzfT + HID * HID);  // 1 KB

    dim3 tg(4, 4, KL + 1);
    prep_transpose<<<tg, 256, 0, stream>>>(Wz, Wzf, bz, WzT, WzfT, bzsum);
    ptree_kernel<<<TREES / GB, 256, 0, stream>>>(x, leaf, bzf, WzT, WzfT, bzsum,
                                                 (float*)d_out, 200000);
}

// Round 2
// 492.111 us; speedup vs baseline: 1.1173x; 1.1173x over previous
//
#include <hip/hip_runtime.h>
#include <stdint.h>

#define TREES 8192
#define HID   256
#define CH    16
#define KL    4
#define GB    16           // trees per block
#define CKT   4            // trees per chunk
#define NC    (GB / CKT)   // 4 chunks per block
#define LDSS  264          // LDS row stride in bf16 elems (256 + 8 pad)

typedef short bf16x8 __attribute__((ext_vector_type(8)));
typedef float f32x4  __attribute__((ext_vector_type(4)));

__device__ __forceinline__ unsigned short f2bf(float f) {
    unsigned u = __builtin_bit_cast(unsigned, f);
    u += 0x7FFFu + ((u >> 16) & 1u);
    return (unsigned short)(u >> 16);
}
__device__ __forceinline__ float elu1(float x) {
    return x > 0.f ? x : (__expf(x) - 1.f);
}
__device__ __forceinline__ uint4 pack8(float4 a, float4 b) {
    union { uint4 u4; unsigned short s[8]; } U;
    U.s[0] = f2bf(a.x); U.s[1] = f2bf(a.y); U.s[2] = f2bf(a.z); U.s[3] = f2bf(a.w);
    U.s[4] = f2bf(b.x); U.s[5] = f2bf(b.y); U.s[6] = f2bf(b.z); U.s[7] = f2bf(b.w);
    return U.u4;
}

// ---- Prep: tiled transpose fp32 [h][d] -> bf16 [d][h], coalesced both sides.
// grid (4,4,5): z = 0..3 -> Wz layer k, z = 4 -> Wzf. Block (0,0,4) also does bzsum.
__global__ void prep_transpose(const float* __restrict__ Wz,
                               const float* __restrict__ Wzf,
                               const float* __restrict__ bz,
                               unsigned short* __restrict__ WzT,
                               unsigned short* __restrict__ WzfT,
                               float* __restrict__ bzsum) {
    __shared__ unsigned short ts[64][65];
    const int k  = blockIdx.z;
    const int h0 = blockIdx.x * 64;
    const int d0 = blockIdx.y * 64;
    const float* src = (k < KL) ? (Wz + (k << 16)) : Wzf;
    unsigned short* dst = (k < KL) ? (WzT + (k << 16)) : WzfT;
    const int tid = threadIdx.x;
    const int jc  = tid & 63;
    #pragma unroll
    for (int r = 0; r < 16; ++r) {
        int i = r * 4 + (tid >> 6);
        ts[jc][i] = f2bf(src[(h0 + i) * HID + d0 + jc]);   // coalesced read
    }
    __syncthreads();
    #pragma unroll
    for (int r = 0; r < 16; ++r) {
        int jl = r * 4 + (tid >> 6);
        dst[(d0 + jl) * HID + h0 + jc] = ts[jl][jc];       // coalesced write
    }
    if (k == KL && blockIdx.x == 0 && blockIdx.y == 0) {
        float s = 0.f;
        #pragma unroll
        for (int kk = 0; kk < KL; ++kk) s += bz[kk * HID + tid];
        bzsum[tid] = s;
    }
}

// ---- Main: 16 trees/block, 4 chunks of 4 trees, double-buffered LDS gather.
// Next chunk's x rows are staged in PAIRS of cells (16 VGPRs in flight, not 64):
// pair p issued at k-iter p, written at k-iter p+1 (8 kt-steps of MFMA cover).
// Leaf indices prefetched one chunk ahead. Weights: depth-2 rotating prefetch.
__global__ __launch_bounds__(256, 2) void ptree_kernel(
    const float* __restrict__ x,               // [N,256] fp32
    const int* __restrict__ leaf,              // [T,16]
    const float* __restrict__ bzf,             // [256] fp32
    const unsigned short* __restrict__ WzT,    // [K][d][h] bf16 (ws)
    const unsigned short* __restrict__ WzfT,   // [d][h] bf16 (ws)
    const float* __restrict__ bzsum,           // [256] f32 (ws)
    float* __restrict__ out,                   // [T,256] fp32
    int nrows)
{
    __shared__ __align__(16) unsigned short sh[2][CKT][CH][LDSS]; // 2 x 33 KB
    __shared__ __align__(16) unsigned short hs[GB][LDSS];         // 16 tree rows
    const int tid  = threadIdx.x;
    const int lane = tid & 63;
    const int wave = tid >> 6;
    const int t0   = blockIdx.x * GB;
    const int ncol = lane & 15;
    const int quad = lane >> 4;
    const int ch   = tid & 31;   // 8-float column chunk within a row
    const int q5   = tid >> 5;   // 0..7
    // cell i (0..7): tree g = i>>1, child row = ((i&1)<<3)+q5
    // -> pair P = cells {2P, 2P+1} = tree P, rows {q5, 8+q5}

    // ---- prologue: gather chunk 0 straight into sh[0] (exposed once)
    #pragma unroll
    for (int i = 0; i < 8; ++i) {
        const int g = i >> 1, row = ((i & 1) << 3) + q5;
        int idx = leaf[(t0 + g) * CH + row];
        idx = ((unsigned)idx < (unsigned)nrows) ? idx : 0;
        const float* src = x + (size_t)idx * HID + ch * 8;
        float4 v0 = *(const float4*)src;
        float4 v1 = *(const float4*)(src + 4);
        *(uint4*)&sh[0][g][row][ch * 8] = pack8(v0, v1);
    }
    // leaf-index prefetch for chunk 1
    int idxp[8];
    #pragma unroll
    for (int i = 0; i < 8; ++i) {
        const int g = i >> 1, row = ((i & 1) << 3) + q5;
        int idx = leaf[(t0 + CKT + g) * CH + row];
        idxp[i] = ((unsigned)idx < (unsigned)nrows) ? idx : 0;
    }

    float bzs[4], bzfv[4];
    #pragma unroll
    for (int nt = 0; nt < 4; ++nt) {
        bzs[nt]  = bzsum[wave * 64 + nt * 16 + ncol];
        bzfv[nt] = bzf[wave * 64 + nt * 16 + ncol];
    }

    // weight fragment pipeline, depth 2 (slot = s&1; period 32 -> chunk-periodic)
    const unsigned short* wz_base = WzT + (wave * 64 + ncol) * HID + quad * 8;
    bf16x8 bp[2][4];
    #pragma unroll
    for (int s = 0; s < 2; ++s) {
        const unsigned short* p = wz_base + (s >> 3) * 65536 + (s & 7) * 32;
        #pragma unroll
        for (int nt = 0; nt < 4; ++nt) bp[s][nt] = *(const bf16x8*)(p + nt * 16 * HID);
    }

    __syncthreads();

    float4 xa[4];   // ONE pair in flight: tree P, rows q5 / 8+q5 (16 VGPRs)

#define ISSUE_PAIR(P) do {                                                   \
        const float* s0_ = x + (size_t)idxp[2*(P)]     * HID + ch * 8;       \
        const float* s1_ = x + (size_t)idxp[2*(P) + 1] * HID + ch * 8;       \
        xa[0] = *(const float4*)s0_;  xa[1] = *(const float4*)(s0_ + 4);     \
        xa[2] = *(const float4*)s1_;  xa[3] = *(const float4*)(s1_ + 4);     \
    } while (0)

#define WRITE_PAIR(P) do {                                                   \
        *(uint4*)&shn[(P)][q5][ch * 8]     = pack8(xa[0], xa[1]);            \
        *(uint4*)&shn[(P)][8 + q5][ch * 8] = pack8(xa[2], xa[3]);            \
    } while (0)

    for (int c = 0; c < NC; ++c) {
        const int pb   = c & 1;
        const int more = (c < NC - 1);
        unsigned short (*shn)[CH][LDSS] = sh[pb ^ 1];

        if (more) ISSUE_PAIR(0);

        f32x4 acc1[CKT][4];
        #pragma unroll
        for (int g = 0; g < CKT; ++g)
            #pragma unroll
            for (int nt = 0; nt < 4; ++nt) acc1[g][nt] = f32x4{0.f, 0.f, 0.f, 0.f};

        #pragma unroll
        for (int k = 0; k < KL; ++k) {
            if (more) {
                if (k == 1) { WRITE_PAIR(0); ISSUE_PAIR(1); }
                if (k == 2) { WRITE_PAIR(1); ISSUE_PAIR(2); }
                if (k == 3) {
                    WRITE_PAIR(2); ISSUE_PAIR(3);
                    if (c + 2 < NC) {       // leaf indices for chunk c+2
                        #pragma unroll
                        for (int i = 0; i < 8; ++i) {
                            const int g = i >> 1, row = ((i & 1) << 3) + q5;
                            int idx = leaf[(t0 + (c + 2) * CKT + g) * CH + row];
                            idxp[i] = ((unsigned)idx < (unsigned)nrows) ? idx : 0;
                        }
                    }
                }
            }
            const int arow = (ncol - k) & 15;
            #pragma unroll
            for (int kt = 0; kt < 8; ++kt) {
                const int s = k * 8 + kt;
                #pragma unroll
                for (int g = 0; g < CKT; ++g) {
                    bf16x8 a = *(const bf16x8*)&sh[pb][g][arow][kt * 32 + quad * 8];
                    #pragma unroll
                    for (int nt = 0; nt < 4; ++nt)
                        acc1[g][nt] = __builtin_amdgcn_mfma_f32_16x16x32_bf16(
                            a, bp[s & 1][nt], acc1[g][nt], 0, 0, 0);
                }
                // prefetch weights for step s+2 into the slot just consumed
                const int sn = (s + 2) & 31;
                const unsigned short* pn = wz_base + (sn >> 3) * 65536 + (sn & 7) * 32;
                #pragma unroll
                for (int nt = 0; nt < 4; ++nt)
                    bp[s & 1][nt] = *(const bf16x8*)(pn + nt * 16 * HID);
            }
        }
        if (more) WRITE_PAIR(3);

        // hsum: +bz, ELU, sum over 16 children -> hs row (c*4+g)
        #pragma unroll
        for (int g = 0; g < CKT; ++g)
            #pragma unroll
            for (int nt = 0; nt < 4; ++nt) {
                float sv = 0.f;
                #pragma unroll
                for (int r = 0; r < 4; ++r) sv += elu1(acc1[g][nt][r] + bzs[nt]);
                sv += __shfl_xor(sv, 16);
                sv += __shfl_xor(sv, 32);
                if (quad == 0) hs[c * CKT + g][wave * 64 + nt * 16 + ncol] = f2bf(sv);
            }

        __syncthreads();   // next-buffer writes visible; current-buffer reads done
    }

#undef ISSUE_PAIR
#undef WRITE_PAIR

    // ---- GEMM2: all 16 hs rows valid -> no masking, no wasted rows.
    f32x4 acc2[4];
    #pragma unroll
    for (int nt = 0; nt < 4; ++nt) acc2[nt] = f32x4{0.f, 0.f, 0.f, 0.f};

    const unsigned short* wzf_base = WzfT + (wave * 64 + ncol) * HID + quad * 8;
    #pragma unroll
    for (int kt = 0; kt < 8; ++kt) {
        bf16x8 a = *(const bf16x8*)&hs[ncol][kt * 32 + quad * 8];
        #pragma unroll
        for (int nt = 0; nt < 4; ++nt) {
            bf16x8 b = *(const bf16x8*)(wzf_base + nt * 16 * HID + kt * 32);
            acc2[nt] = __builtin_amdgcn_mfma_f32_16x16x32_bf16(a, b, acc2[nt], 0, 0, 0);
        }
    }

    #pragma unroll
    for (int nt = 0; nt < 4; ++nt)
        #pragma unroll
        for (int r = 0; r < 4; ++r) {
            const int tree = quad * 4 + r;   // 0..15, all valid
            float v = elu1(acc2[nt][r] + 16.f * bzfv[nt]);
            out[(size_t)(t0 + tree) * HID + wave * 64 + nt * 16 + ncol] = v;
        }
}

extern "C" void kernel_launch(void* const* d_in, const int* in_sizes, int n_in,
                              void* d_out, int out_size, void* d_ws, size_t ws_size,
                              hipStream_t stream) {
    (void)out_size; (void)ws_size;
    const void* p_x = nullptr; const void* p_Wz = nullptr; const void* p_bz = nullptr;
    const void* p_Wzf = nullptr; const void* p_bzf = nullptr; const void* p_leaf = nullptr;
    for (int i = 0; i < n_in; ++i) {
        switch (in_sizes[i]) {
            case 200000 * 256:   p_x    = d_in[i]; break;
            case KL * 256 * 256: p_Wz   = d_in[i]; break;
            case KL * 256:       p_bz   = d_in[i]; break;
            case 256 * 256:      p_Wzf  = d_in[i]; break;
            case 256:            p_bzf  = d_in[i]; break;
            case TREES * CH:     p_leaf = d_in[i]; break;
        }
    }
    const float* x    = (const float*)p_x;
    const float* Wz   = (const float*)p_Wz;
    const float* bz   = (const float*)p_bz;
    const float* Wzf  = (const float*)p_Wzf;
    const float* bzf  = (const float*)p_bzf;
    const int*   leaf = (const int*)p_leaf;

    unsigned short* WzT  = (unsigned short*)d_ws;        // 512 KB
    unsigned short* WzfT = WzT + KL * HID * HID;         // 128 KB
    float*          bzsum = (float*)(WzfT + HID * HID);  // 1 KB

    dim3 tg(4, 4, KL + 1);
    prep_transpose<<<tg, 256, 0, stream>>>(Wz, Wzf, bz, WzT, WzfT, bzsum);
    ptree_kernel<<<TREES / GB, 256, 0, stream>>>(x, leaf, bzf, WzT, WzfT, bzsum,
                                                 (float*)d_out, 200000);
}

// Round 3
// 407.653 us; speedup vs baseline: 1.3487x; 1.2072x over previous
//
#include <hip/hip_runtime.h>
#include <stdint.h>

#define TREES 8192
#define HID   256
#define CH    16
#define KL    4
#define G     4            // trees per block (small block -> high occupancy)
#define LDSS  264          // LDS row stride in bf16 elems (256 + 8 pad)

typedef short bf16x8 __attribute__((ext_vector_type(8)));
typedef float f32x4  __attribute__((ext_vector_type(4)));

__device__ __forceinline__ unsigned short f2bf(float f) {
    unsigned u = __builtin_bit_cast(unsigned, f);
    u += 0x7FFFu + ((u >> 16) & 1u);
    return (unsigned short)(u >> 16);
}
__device__ __forceinline__ float elu1(float x) {
    return x > 0.f ? x : (__expf(x) - 1.f);
}
__device__ __forceinline__ uint4 pack8(float4 a, float4 b) {
    union { uint4 u4; unsigned short s[8]; } U;
    U.s[0] = f2bf(a.x); U.s[1] = f2bf(a.y); U.s[2] = f2bf(a.z); U.s[3] = f2bf(a.w);
    U.s[4] = f2bf(b.x); U.s[5] = f2bf(b.y); U.s[6] = f2bf(b.z); U.s[7] = f2bf(b.w);
    return U.u4;
}

// ---- Prep: tiled transpose fp32 [h][d] -> bf16 [d][h], coalesced both sides.
// grid (4,4,5): z = 0..3 -> Wz layer k, z = 4 -> Wzf. Block (0,0,4) also does bzsum.
__global__ void prep_transpose(const float* __restrict__ Wz,
                               const float* __restrict__ Wzf,
                               const float* __restrict__ bz,
                               unsigned short* __restrict__ WzT,
                               unsigned short* __restrict__ WzfT,
                               float* __restrict__ bzsum) {
    __shared__ unsigned short ts[64][65];
    const int k  = blockIdx.z;
    const int h0 = blockIdx.x * 64;
    const int d0 = blockIdx.y * 64;
    const float* src = (k < KL) ? (Wz + (k << 16)) : Wzf;
    unsigned short* dst = (k < KL) ? (WzT + (k << 16)) : WzfT;
    const int tid = threadIdx.x;
    const int jc  = tid & 63;
    #pragma unroll
    for (int r = 0; r < 16; ++r) {
        int i = r * 4 + (tid >> 6);
        ts[jc][i] = f2bf(src[(h0 + i) * HID + d0 + jc]);   // coalesced read
    }
    __syncthreads();
    #pragma unroll
    for (int r = 0; r < 16; ++r) {
        int jl = r * 4 + (tid >> 6);
        dst[(d0 + jl) * HID + h0 + jc] = ts[jl][jc];       // coalesced write
    }
    if (k == KL && blockIdx.x == 0 && blockIdx.y == 0) {
        float s = 0.f;
        #pragma unroll
        for (int kk = 0; kk < KL; ++kk) s += bz[kk * HID + tid];
        bzsum[tid] = s;
    }
}

// ---- Main: G=4 trees/block, single-buffer LDS (36 KB), no manual prefetch
// registers. Latency hiding comes from occupancy (3+ blocks/CU) instead of
// in-wave pipelining — structurally spill-free (acc 64 AGPR + ~90 arch VGPR).
__global__ __launch_bounds__(256, 3) void ptree_kernel(
    const float* __restrict__ x,               // [N,256] fp32
    const int* __restrict__ leaf,              // [T,16]
    const float* __restrict__ bzf,             // [256] fp32
    const unsigned short* __restrict__ WzT,    // [K][d][h] bf16 (ws)
    const unsigned short* __restrict__ WzfT,   // [d][h] bf16 (ws)
    const float* __restrict__ bzsum,           // [256] f32 (ws)
    float* __restrict__ out,                   // [T,256] fp32
    int nrows)
{
    __shared__ __align__(16) unsigned short sh[G][CH][LDSS];  // 33.8 KB
    __shared__ __align__(16) unsigned short hs[G][LDSS];      // 2.1 KB
    const int tid  = threadIdx.x;
    const int lane = tid & 63;
    const int wave = tid >> 6;
    const int t0   = blockIdx.x * G;
    const int ncol = lane & 15;
    const int quad = lane >> 4;

    // ---- Gather x rows for G trees into LDS as bf16 (2x float4 -> 16B write).
    // 4 trees x 16 rows x 32 chunks = 2048 cells / 256 threads = 8 iters, all
    // independent -> compiler batches the leaf loads then the x loads (ILP).
    #pragma unroll
    for (int i = 0; i < (G * CH * 32) / 256; ++i) {   // 8 iters
        int cid = i * 256 + tid;
        int g   = cid >> 9;
        int row = (cid >> 5) & 15;
        int ch  = cid & 31;
        int idx = leaf[(t0 + g) * CH + row];
        idx = ((unsigned)idx < (unsigned)nrows) ? idx : 0;
        const float* src = x + (size_t)idx * HID + ch * 8;
        float4 v0 = *(const float4*)src;
        float4 v1 = *(const float4*)(src + 4);
        *(uint4*)&sh[g][row][ch * 8] = pack8(v0, v1);
    }

    float bzs[4], bzfv[4];
    #pragma unroll
    for (int nt = 0; nt < 4; ++nt) {
        bzs[nt]  = bzsum[wave * 64 + nt * 16 + ncol];
        bzfv[nt] = bzf[wave * 64 + nt * 16 + ncol];
    }

    __syncthreads();

    // ---- GEMM1: rolled_sum[c][d] = sum_k data[(c-k)&15][:] @ Wz[k][:][d]
    // Direct B-frag loads (L2-resident WzT); TLP + unroll-4 window hide latency.
    f32x4 acc1[G][4];
    #pragma unroll
    for (int g = 0; g < G; ++g)
        #pragma unroll
        for (int nt = 0; nt < 4; ++nt) acc1[g][nt] = f32x4{0.f, 0.f, 0.f, 0.f};

    const unsigned short* wz_base = WzT + (wave * 64 + ncol) * HID + quad * 8;

    #pragma unroll 4
    for (int s = 0; s < KL * 8; ++s) {
        const int k  = s >> 3;
        const int kt = s & 7;
        const unsigned short* bp = wz_base + k * 65536 + kt * 32;
        bf16x8 b[4];
        #pragma unroll
        for (int nt = 0; nt < 4; ++nt)
            b[nt] = *(const bf16x8*)(bp + nt * 16 * HID);
        const int arow = (ncol - k) & 15;
        #pragma unroll
        for (int g = 0; g < G; ++g) {
            bf16x8 a = *(const bf16x8*)&sh[g][arow][kt * 32 + quad * 8];
            #pragma unroll
            for (int nt = 0; nt < 4; ++nt)
                acc1[g][nt] = __builtin_amdgcn_mfma_f32_16x16x32_bf16(
                    a, b[nt], acc1[g][nt], 0, 0, 0);
        }
    }

    // ---- hsum: +bz, ELU per (child,d), sum over 16 children in-register.
    //      C-layout: col=ncol (d), row=quad*4+r (child). xor-shfl sums quads.
    #pragma unroll
    for (int g = 0; g < G; ++g)
        #pragma unroll
        for (int nt = 0; nt < 4; ++nt) {
            float sv = 0.f;
            #pragma unroll
            for (int r = 0; r < 4; ++r) sv += elu1(acc1[g][nt][r] + bzs[nt]);
            sv += __shfl_xor(sv, 16);
            sv += __shfl_xor(sv, 32);
            if (quad == 0) hs[g][wave * 64 + nt * 16 + ncol] = f2bf(sv);
        }

    __syncthreads();

    // ---- GEMM2 (tiny): out[t][d] = elu(hsum[t][:] @ Wzf[:][d] + 16*bzf[d])
    //      A rows = trees (4 valid of 16, rest zeroed).
    f32x4 acc2[4];
    #pragma unroll
    for (int nt = 0; nt < 4; ++nt) acc2[nt] = f32x4{0.f, 0.f, 0.f, 0.f};

    const unsigned short* wzf_base = WzfT + (wave * 64 + ncol) * HID + quad * 8;
    #pragma unroll
    for (int kt = 0; kt < 8; ++kt) {
        bf16x8 a = *(const bf16x8*)&hs[ncol & (G - 1)][kt * 32 + quad * 8];
        if (ncol >= G) a = bf16x8{0, 0, 0, 0, 0, 0, 0, 0};
        #pragma unroll
        for (int nt = 0; nt < 4; ++nt) {
            bf16x8 b = *(const bf16x8*)(wzf_base + nt * 16 * HID + kt * 32);
            acc2[nt] = __builtin_amdgcn_mfma_f32_16x16x32_bf16(a, b, acc2[nt], 0, 0, 0);
        }
    }

    // ---- Store: row=quad*4+r is the tree (0..3 valid), col=d.
    #pragma unroll
    for (int nt = 0; nt < 4; ++nt)
        #pragma unroll
        for (int r = 0; r < 4; ++r) {
            int tree = quad * 4 + r;
            if (tree < G) {
                float v = elu1(acc2[nt][r] + 16.f * bzfv[nt]);
                out[(size_t)(t0 + tree) * HID + wave * 64 + nt * 16 + ncol] = v;
            }
        }
}

extern "C" void kernel_launch(void* const* d_in, const int* in_sizes, int n_in,
                              void* d_out, int out_size, void* d_ws, size_t ws_size,
                              hipStream_t stream) {
    (void)out_size; (void)ws_size;
    const void* p_x = nullptr; const void* p_Wz = nullptr; const void* p_bz = nullptr;
    const void* p_Wzf = nullptr; const void* p_bzf = nullptr; const void* p_leaf = nullptr;
    for (int i = 0; i < n_in; ++i) {
        switch (in_sizes[i]) {
            case 200000 * 256:   p_x    = d_in[i]; break;
            case KL * 256 * 256: p_Wz   = d_in[i]; break;
            case KL * 256:       p_bz   = d_in[i]; break;
            case 256 * 256:      p_Wzf  = d_in[i]; break;
            case 256:            p_bzf  = d_in[i]; break;
            case TREES * CH:     p_leaf = d_in[i]; break;
        }
    }
    const float* x    = (const float*)p_x;
    const float* Wz   = (const float*)p_Wz;
    const float* bz   = (const float*)p_bz;
    const float* Wzf  = (const float*)p_Wzf;
    const float* bzf  = (const float*)p_bzf;
    const int*   leaf = (const int*)p_leaf;

    unsigned short* WzT  = (unsigned short*)d_ws;        // 512 KB
    unsigned short* WzfT = WzT + KL * HID * HID;         // 128 KB
    float*          bzsum = (float*)(WzfT + HID * HID);  // 1 KB

    dim3 tg(4, 4, KL + 1);
    prep_transpose<<<tg, 256, 0, stream>>>(Wz, Wzf, bz, WzT, WzfT, bzsum);
    ptree_kernel<<<TREES / G, 256, 0, stream>>>(x, leaf, bzf, WzT, WzfT, bzsum,
                                                (float*)d_out, 200000);
}

// Round 4
// 378.046 us; speedup vs baseline: 1.4544x; 1.0783x over previous
//
#include <hip/hip_runtime.h>
#include <stdint.h>

#define TREES 8192
#define HID   256
#define CH    16
#define KL    4
#define G     4            // trees per block
#define NSTEP (KL * 8)     // 32 MFMA k-steps

typedef short bf16x8 __attribute__((ext_vector_type(8)));
typedef float f32x4  __attribute__((ext_vector_type(4)));

__device__ __forceinline__ unsigned short f2bf(float f) {
    unsigned u = __builtin_bit_cast(unsigned, f);
    u += 0x7FFFu + ((u >> 16) & 1u);
    return (unsigned short)(u >> 16);
}
__device__ __forceinline__ float elu1(float x) {
    return x > 0.f ? x : (__expf(x) - 1.f);
}
__device__ __forceinline__ uint4 pack8(float4 a, float4 b) {
    union { uint4 u4; unsigned short s[8]; } U;
    U.s[0] = f2bf(a.x); U.s[1] = f2bf(a.y); U.s[2] = f2bf(a.z); U.s[3] = f2bf(a.w);
    U.s[4] = f2bf(b.x); U.s[5] = f2bf(b.y); U.s[6] = f2bf(b.z); U.s[7] = f2bf(b.w);
    return U.u4;
}
// async global->LDS, 16 B per lane (m97 pattern). LDS dest must be linear
// (wave-uniform base + lane*16) -- our staging layout is exactly that.
__device__ __forceinline__ void gload_lds16(const void* g, void* l) {
    __builtin_amdgcn_global_load_lds(
        (const __attribute__((address_space(1))) void*)g,
        (__attribute__((address_space(3))) void*)l, 16, 0, 0);
}

// ---- Prep: tiled transpose fp32 [h][d] -> bf16 [d][h], coalesced both sides.
__global__ void prep_transpose(const float* __restrict__ Wz,
                               const float* __restrict__ Wzf,
                               const float* __restrict__ bz,
                               unsigned short* __restrict__ WzT,
                               unsigned short* __restrict__ WzfT,
                               float* __restrict__ bzsum) {
    __shared__ unsigned short ts[64][65];
    const int k  = blockIdx.z;
    const int h0 = blockIdx.x * 64;
    const int d0 = blockIdx.y * 64;
    const float* src = (k < KL) ? (Wz + (k << 16)) : Wzf;
    unsigned short* dst = (k < KL) ? (WzT + (k << 16)) : WzfT;
    const int tid = threadIdx.x;
    const int jc  = tid & 63;
    #pragma unroll
    for (int r = 0; r < 16; ++r) {
        int i = r * 4 + (tid >> 6);
        ts[jc][i] = f2bf(src[(h0 + i) * HID + d0 + jc]);
    }
    __syncthreads();
    #pragma unroll
    for (int r = 0; r < 16; ++r) {
        int jl = r * 4 + (tid >> 6);
        dst[(d0 + jl) * HID + h0 + jc] = ts[jl][jc];
    }
    if (k == KL && blockIdx.x == 0 && blockIdx.y == 0) {
        float s = 0.f;
        #pragma unroll
        for (int kk = 0; kk < KL; ++kk) s += bz[kk * HID + tid];
        bzsum[tid] = s;
    }
}

// ---- Main: G=4 trees/block. A gathered once into XOR-swizzled LDS.
// B (WzT) staged per k-step into double-buffered LDS via global_load_lds:
// stage(s+1) issued before step s's MFMAs, lands under them, barrier flips.
// Removes the per-step L2/L3 demand-load from every wave's critical path.
__global__ __launch_bounds__(256, 2) void ptree_kernel(
    const float* __restrict__ x,               // [N,256] fp32
    const int* __restrict__ leaf,              // [T,16]
    const float* __restrict__ bzf,             // [256] fp32
    const unsigned short* __restrict__ WzT,    // [K][d][h] bf16 (ws)
    const unsigned short* __restrict__ WzfT,   // [d][h] bf16 (ws)
    const float* __restrict__ bzsum,           // [256] f32 (ws)
    float* __restrict__ out,                   // [T,256] fp32
    int nrows)
{
    // A: [G][16 rows][32 chunks of 16B], chunk XOR-swizzled by (row&7): 32 KB
    __shared__ __align__(16) unsigned short shA[G * CH * 256];
    // B: 2 x 16 KB; slot (d, q) at byte d*64 + q*16, holds src quad q^((d>>1)&3)
    __shared__ __align__(16) unsigned short shB[2][8192];
    __shared__ __align__(16) unsigned short hs[G][264];
    const int tid  = threadIdx.x;
    const int lane = tid & 63;
    const int wave = tid >> 6;
    const int t0   = blockIdx.x * G;
    const int ncol = lane & 15;
    const int quad = lane >> 4;

    // ---- per-thread staging geometry (c-independent parts)
    const int dd   = tid >> 2;                       // d within 64-row call slice
    const int q    = tid & 3;
    const int srcq = q ^ ((dd >> 1) & 3);            // pre-swizzled source quad
    const unsigned short* gstage = WzT + dd * HID + srcq * 8;  // + k*65536 + kt*32 + c*16384
    // LDS dest (linear in tid): shorts offset c*2048 + tid*8 within buffer

    // ---- issue stage(0) first: hides under the whole gather phase
    #pragma unroll
    for (int c = 0; c < 4; ++c)
        gload_lds16(gstage + c * 16384, &shB[0][c * 2048 + tid * 8]);

    // ---- gather A: 4 trees x 16 rows x 32 chunks = 2048 cells / 256 thr
    #pragma unroll
    for (int i = 0; i < 8; ++i) {
        int cid = i * 256 + tid;
        int g   = cid >> 9;
        int row = (cid >> 5) & 15;
        int ch  = cid & 31;
        int idx = leaf[(t0 + g) * CH + row];
        idx = ((unsigned)idx < (unsigned)nrows) ? idx : 0;
        const float* src = x + (size_t)idx * HID + ch * 8;
        float4 v0 = *(const float4*)src;
        float4 v1 = *(const float4*)(src + 4);
        *(uint4*)&shA[(g * CH + row) * 256 + ((ch ^ (row & 7)) * 8)] = pack8(v0, v1);
    }

    float bzs[4], bzfv[4];
    #pragma unroll
    for (int nt = 0; nt < 4; ++nt) {
        bzs[nt]  = bzsum[wave * 64 + nt * 16 + ncol];
        bzfv[nt] = bzf[wave * 64 + nt * 16 + ncol];
    }

    // ---- per-lane B-read offsets (shorts), constant across steps
    int boff[4];
    #pragma unroll
    for (int nt = 0; nt < 4; ++nt) {
        const int d = wave * 64 + nt * 16 + ncol;
        boff[nt] = d * 32 + ((quad ^ ((d >> 1) & 3)) * 8);
    }

    __syncthreads();   // A-tile + stage(0) ready (drains vmcnt+lgkmcnt)

    f32x4 acc1[G][4];
    #pragma unroll
    for (int g = 0; g < G; ++g)
        #pragma unroll
        for (int nt = 0; nt < 4; ++nt) acc1[g][nt] = f32x4{0.f, 0.f, 0.f, 0.f};

    #pragma unroll 2
    for (int s = 0; s < NSTEP; ++s) {
        const int k  = s >> 3;
        const int kt = s & 7;
        // stage next step's B tile into the other buffer (issue-and-forget)
        if (s < NSTEP - 1) {
            const int sn = s + 1;
            const unsigned short* gsrc = gstage + (sn >> 3) * 65536 + (sn & 7) * 32;
            unsigned short* ldst = &shB[sn & 1][tid * 8];
            #pragma unroll
            for (int c = 0; c < 4; ++c)
                gload_lds16(gsrc + c * 16384, ldst + c * 2048);
        }
        // B fragments from the current buffer (swizzled slots)
        bf16x8 bfr[4];
        #pragma unroll
        for (int nt = 0; nt < 4; ++nt)
            bfr[nt] = *(const bf16x8*)&shB[s & 1][boff[nt]];
        // A fragments + MFMA
        const int arow  = (ncol - k) & 15;
        const int abase = arow * 256 + (((kt * 4 + quad) ^ (arow & 7)) * 8);
        #pragma unroll
        for (int g = 0; g < G; ++g) {
            bf16x8 a = *(const bf16x8*)&shA[g * (CH * 256) + abase];
            #pragma unroll
            for (int nt = 0; nt < 4; ++nt)
                acc1[g][nt] = __builtin_amdgcn_mfma_f32_16x16x32_bf16(
                    a, bfr[nt], acc1[g][nt], 0, 0, 0);
        }
        __syncthreads();   // stage(s+1) landed; all reads of buf s&1 done
    }

    // ---- hsum: +bz, ELU, sum over 16 children -> hs[g]
    #pragma unroll
    for (int g = 0; g < G; ++g)
        #pragma unroll
        for (int nt = 0; nt < 4; ++nt) {
            float sv = 0.f;
            #pragma unroll
            for (int r = 0; r < 4; ++r) sv += elu1(acc1[g][nt][r] + bzs[nt]);
            sv += __shfl_xor(sv, 16);
            sv += __shfl_xor(sv, 32);
            if (quad == 0) hs[g][wave * 64 + nt * 16 + ncol] = f2bf(sv);
        }

    __syncthreads();

    // ---- GEMM2: out[t][d] = elu(hsum[t][:] @ Wzf[:][d] + 16*bzf[d])
    f32x4 acc2[4];
    #pragma unroll
    for (int nt = 0; nt < 4; ++nt) acc2[nt] = f32x4{0.f, 0.f, 0.f, 0.f};

    const unsigned short* wzf_base = WzfT + (wave * 64 + ncol) * HID + quad * 8;
    #pragma unroll
    for (int kt = 0; kt < 8; ++kt) {
        bf16x8 a = *(const bf16x8*)&hs[ncol & (G - 1)][kt * 32 + quad * 8];
        if (ncol >= G) a = bf16x8{0, 0, 0, 0, 0, 0, 0, 0};
        #pragma unroll
        for (int nt = 0; nt < 4; ++nt) {
            bf16x8 b = *(const bf16x8*)(wzf_base + nt * 16 * HID + kt * 32);
            acc2[nt] = __builtin_amdgcn_mfma_f32_16x16x32_bf16(a, b, acc2[nt], 0, 0, 0);
        }
    }

    #pragma unroll
    for (int nt = 0; nt < 4; ++nt)
        #pragma unroll
        for (int r = 0; r < 4; ++r) {
            int tree = quad * 4 + r;
            if (tree < G) {
                float v = elu1(acc2[nt][r] + 16.f * bzfv[nt]);
                out[(size_t)(t0 + tree) * HID + wave * 64 + nt * 16 + ncol] = v;
            }
        }
}

extern "C" void kernel_launch(void* const* d_in, const int* in_sizes, int n_in,
                              void* d_out, int out_size, void* d_ws, size_t ws_size,
                              hipStream_t stream) {
    (void)out_size; (void)ws_size;
    const void* p_x = nullptr; const void* p_Wz = nullptr; const void* p_bz = nullptr;
    const void* p_Wzf = nullptr; const void* p_bzf = nullptr; const void* p_leaf = nullptr;
    for (int i = 0; i < n_in; ++i) {
        switch (in_sizes[i]) {
            case 200000 * 256:   p_x    = d_in[i]; break;
            case KL * 256 * 256: p_Wz   = d_in[i]; break;
            case KL * 256:       p_bz   = d_in[i]; break;
            case 256 * 256:      p_Wzf  = d_in[i]; break;
            case 256:            p_bzf  = d_in[i]; break;
            case TREES * CH:     p_leaf = d_in[i]; break;
        }
    }
    const float* x    = (const float*)p_x;
    const float* Wz   = (const float*)p_Wz;
    const float* bz   = (const float*)p_bz;
    const float* Wzf  = (const float*)p_Wzf;
    const float* bzf  = (const float*)p_bzf;
    const int*   leaf = (const int*)p_leaf;

    unsigned short* WzT  = (unsigned short*)d_ws;        // 512 KB
    unsigned short* WzfT = WzT + KL * HID * HID;         // 128 KB
    float*          bzsum = (float*)(WzfT + HID * HID);  // 1 KB

    dim3 tg(4, 4, KL + 1);
    prep_transpose<<<tg, 256, 0, stream>>>(Wz, Wzf, bz, WzT, WzfT, bzsum);
    ptree_kernel<<<TREES / G, 256, 0, stream>>>(x, leaf, bzf, WzT, WzfT, bzsum,
                                                (float*)d_out, 200000);
}

// Round 5
// 342.080 us; speedup vs baseline: 1.6073x; 1.1051x over previous
//
#include <hip/hip_runtime.h>
#include <stdint.h>

#define TREES 8192
#define HID   256
#define CH    16
#define KL    4
#define G     8            // trees per group (r0's proven inner-loop size)
#define NG    2            // groups per block -> 16 trees/block
#define GB    (G * NG)
#define LDSS  264          // LDS row stride in bf16 elems (256 + 8 pad)

typedef short bf16x8 __attribute__((ext_vector_type(8)));
typedef float f32x4  __attribute__((ext_vector_type(4)));

__device__ __forceinline__ unsigned short f2bf(float f) {
    unsigned u = __builtin_bit_cast(unsigned, f);
    u += 0x7FFFu + ((u >> 16) & 1u);
    return (unsigned short)(u >> 16);
}
__device__ __forceinline__ float elu1(float x) {
    return x > 0.f ? x : (__expf(x) - 1.f);
}
__device__ __forceinline__ uint4 pack8(float4 a, float4 b) {
    union { uint4 u4; unsigned short s[8]; } U;
    U.s[0] = f2bf(a.x); U.s[1] = f2bf(a.y); U.s[2] = f2bf(a.z); U.s[3] = f2bf(a.w);
    U.s[4] = f2bf(b.x); U.s[5] = f2bf(b.y); U.s[6] = f2bf(b.z); U.s[7] = f2bf(b.w);
    return U.u4;
}

// ---- Prep: tiled transpose fp32 [h][d] -> bf16 [d][h], coalesced both sides.
// grid (4,4,5): z = 0..3 -> Wz layer k, z = 4 -> Wzf. Block (0,0,4) also does bzsum.
__global__ void prep_transpose(const float* __restrict__ Wz,
                               const float* __restrict__ Wzf,
                               const float* __restrict__ bz,
                               unsigned short* __restrict__ WzT,
                               unsigned short* __restrict__ WzfT,
                               float* __restrict__ bzsum) {
    __shared__ unsigned short ts[64][65];
    const int k  = blockIdx.z;
    const int h0 = blockIdx.x * 64;
    const int d0 = blockIdx.y * 64;
    const float* src = (k < KL) ? (Wz + (k << 16)) : Wzf;
    unsigned short* dst = (k < KL) ? (WzT + (k << 16)) : WzfT;
    const int tid = threadIdx.x;
    const int jc  = tid & 63;
    #pragma unroll
    for (int r = 0; r < 16; ++r) {
        int i = r * 4 + (tid >> 6);
        ts[jc][i] = f2bf(src[(h0 + i) * HID + d0 + jc]);   // coalesced read
    }
    __syncthreads();
    #pragma unroll
    for (int r = 0; r < 16; ++r) {
        int jl = r * 4 + (tid >> 6);
        dst[(d0 + jl) * HID + h0 + jc] = ts[jl][jc];       // coalesced write
    }
    if (k == KL && blockIdx.x == 0 && blockIdx.y == 0) {
        float s = 0.f;
        #pragma unroll
        for (int kk = 0; kk < KL; ++kk) s += bz[kk * HID + tid];
        bzsum[tid] = s;
    }
}

// ---- Main: 16 trees/block as 2 sequential groups of 8 (r0 inner structure
// verbatim). Amortizes the per-block 640 KB WzT re-stream over 2x the trees
// (512 blocks total -> one residency generation) and makes GEMM2 fully dense
// (16/16 valid A rows). No register staging -> structurally spill-free.
__global__ __launch_bounds__(256, 2) void ptree_kernel(
    const float* __restrict__ x,               // [N,256] fp32
    const int* __restrict__ leaf,              // [T,16]
    const float* __restrict__ bzf,             // [256] fp32
    const unsigned short* __restrict__ WzT,    // [K][d][h] bf16 (ws)
    const unsigned short* __restrict__ WzfT,   // [d][h] bf16 (ws)
    const float* __restrict__ bzsum,           // [256] f32 (ws)
    float* __restrict__ out,                   // [T,256] fp32
    int nrows)
{
    __shared__ __align__(16) unsigned short sh[G][CH][LDSS];  // 67.6 KB
    __shared__ __align__(16) unsigned short hs[GB][LDSS];     // 8.4 KB
    const int tid  = threadIdx.x;
    const int lane = tid & 63;
    const int wave = tid >> 6;
    const int t0   = blockIdx.x * GB;
    const int ncol = lane & 15;
    const int quad = lane >> 4;

    float bzs[4], bzfv[4];
    #pragma unroll
    for (int nt = 0; nt < 4; ++nt) {
        bzs[nt]  = bzsum[wave * 64 + nt * 16 + ncol];
        bzfv[nt] = bzf[wave * 64 + nt * 16 + ncol];
    }

    const unsigned short* wz_base = WzT + (wave * 64 + ncol) * HID + quad * 8;

    for (int grp = 0; grp < NG; ++grp) {
        const int tg = t0 + grp * G;

        // ---- Gather x rows for this group's 8 trees into LDS as bf16.
        #pragma unroll
        for (int i = 0; i < (G * CH * 32) / 256; ++i) {   // 16 iters
            int cid = i * 256 + tid;
            int g   = cid >> 9;
            int row = (cid >> 5) & 15;
            int ch  = cid & 31;
            int idx = leaf[(tg + g) * CH + row];
            idx = ((unsigned)idx < (unsigned)nrows) ? idx : 0;
            const float* src = x + (size_t)idx * HID + ch * 8;
            float4 v0 = *(const float4*)src;
            float4 v1 = *(const float4*)(src + 4);
            *(uint4*)&sh[g][row][ch * 8] = pack8(v0, v1);
        }

        __syncthreads();

        // ---- GEMM1: rolled_sum[c][d] = sum_k data[(c-k)&15][:] @ Wz[k][:][d]
        //      B-frags prefetched 1 step ahead (r0's proven schedule).
        f32x4 acc1[G][4];
        #pragma unroll
        for (int g = 0; g < G; ++g)
            #pragma unroll
            for (int nt = 0; nt < 4; ++nt) acc1[g][nt] = f32x4{0.f, 0.f, 0.f, 0.f};

        bf16x8 bc[4], bn[4];
        #pragma unroll
        for (int nt = 0; nt < 4; ++nt)
            bc[nt] = *(const bf16x8*)(wz_base + nt * 16 * HID);

        #pragma unroll 2
        for (int s = 0; s < KL * 8; ++s) {
            const int sn = (s < KL * 8 - 1) ? s + 1 : s;
            const unsigned short* pn = wz_base + (sn >> 3) * 65536 + (sn & 7) * 32;
            #pragma unroll
            for (int nt = 0; nt < 4; ++nt)
                bn[nt] = *(const bf16x8*)(pn + nt * 16 * HID);
            const int k    = s >> 3;
            const int kt   = s & 7;
            const int arow = (ncol - k) & 15;
            #pragma unroll
            for (int g = 0; g < G; ++g) {
                bf16x8 a = *(const bf16x8*)&sh[g][arow][kt * 32 + quad * 8];
                #pragma unroll
                for (int nt = 0; nt < 4; ++nt)
                    acc1[g][nt] = __builtin_amdgcn_mfma_f32_16x16x32_bf16(
                        a, bc[nt], acc1[g][nt], 0, 0, 0);
            }
            #pragma unroll
            for (int nt = 0; nt < 4; ++nt) bc[nt] = bn[nt];
        }

        // ---- hsum: +bz, ELU per (child,d), sum over 16 children in-register.
        //      C-layout: col=ncol (d), row=quad*4+r (child). xor-shfl sums quads.
        #pragma unroll
        for (int g = 0; g < G; ++g)
            #pragma unroll
            for (int nt = 0; nt < 4; ++nt) {
                float sv = 0.f;
                #pragma unroll
                for (int r = 0; r < 4; ++r) sv += elu1(acc1[g][nt][r] + bzs[nt]);
                sv += __shfl_xor(sv, 16);
                sv += __shfl_xor(sv, 32);
                if (quad == 0) hs[grp * G + g][wave * 64 + nt * 16 + ncol] = f2bf(sv);
            }

        __syncthreads();   // hs visible; sh free for next group's gather
    }

    // ---- GEMM2: all 16 hs rows valid -> dense, no masking.
    f32x4 acc2[4];
    #pragma unroll
    for (int nt = 0; nt < 4; ++nt) acc2[nt] = f32x4{0.f, 0.f, 0.f, 0.f};

    const unsigned short* wzf_base = WzfT + (wave * 64 + ncol) * HID + quad * 8;
    #pragma unroll 2
    for (int kt = 0; kt < 8; ++kt) {
        bf16x8 a = *(const bf16x8*)&hs[ncol][kt * 32 + quad * 8];
        #pragma unroll
        for (int nt = 0; nt < 4; ++nt) {
            bf16x8 b = *(const bf16x8*)(wzf_base + nt * 16 * HID + kt * 32);
            acc2[nt] = __builtin_amdgcn_mfma_f32_16x16x32_bf16(a, b, acc2[nt], 0, 0, 0);
        }
    }

    // ---- Store: row=quad*4+r is the tree (0..15, all valid), col=d.
    #pragma unroll
    for (int nt = 0; nt < 4; ++nt)
        #pragma unroll
        for (int r = 0; r < 4; ++r) {
            const int tree = quad * 4 + r;
            float v = elu1(acc2[nt][r] + 16.f * bzfv[nt]);
            out[(size_t)(t0 + tree) * HID + wave * 64 + nt * 16 + ncol] = v;
        }
}

extern "C" void kernel_launch(void* const* d_in, const int* in_sizes, int n_in,
                              void* d_out, int out_size, void* d_ws, size_t ws_size,
                              hipStream_t stream) {
    (void)out_size; (void)ws_size;
    const void* p_x = nullptr; const void* p_Wz = nullptr; const void* p_bz = nullptr;
    const void* p_Wzf = nullptr; const void* p_bzf = nullptr; const void* p_leaf = nullptr;
    for (int i = 0; i < n_in; ++i) {
        switch (in_sizes[i]) {
            case 200000 * 256:   p_x    = d_in[i]; break;
            case KL * 256 * 256: p_Wz   = d_in[i]; break;
            case KL * 256:       p_bz   = d_in[i]; break;
            case 256 * 256:      p_Wzf  = d_in[i]; break;
            case 256:            p_bzf  = d_in[i]; break;
            case TREES * CH:     p_leaf = d_in[i]; break;
        }
    }
    const float* x    = (const float*)p_x;
    const float* Wz   = (const float*)p_Wz;
    const float* bz   = (const float*)p_bz;
    const float* Wzf  = (const float*)p_Wzf;
    const float* bzf  = (const float*)p_bzf;
    const int*   leaf = (const int*)p_leaf;

    unsigned short* WzT  = (unsigned short*)d_ws;        // 512 KB
    unsigned short* WzfT = WzT + KL * HID * HID;         // 128 KB
    float*          bzsum = (float*)(WzfT + HID * HID);  // 1 KB

    dim3 tg(4, 4, KL + 1);
    prep_transpose<<<tg, 256, 0, stream>>>(Wz, Wzf, bz, WzT, WzfT, bzsum);
    ptree_kernel<<<TREES / GB, 256, 0, stream>>>(x, leaf, bzf, WzT, WzfT, bzsum,
                                                 (float*)d_out, 200000);
}